// Round 3
// baseline (381.708 us; speedup 1.0000x reference)
//
#include <hip/hip_runtime.h>
#include <float.h>

// FactoredQuantizer: B=8192, M=16, N=256, C=64
// inputs  [B, M, C] fp32
// codebook[M, N, C] fp32
// out = codes [B, M, C] fp32  ++  idx [B, M] (written as fp32 values)

#define BQ 8192
#define MQ 16
#define NQ 256
#define CQ 64
#define RPB 128   // rows per block

// ---------------------------------------------------------------------------
// Kernel 1: c2[m*N+n] = sum_k codebook[(m*N+n)*C+k]^2
// ---------------------------------------------------------------------------
__global__ __launch_bounds__(256) void fq_c2_kernel(
        const float* __restrict__ codebook, float* __restrict__ c2) {
    const int wave = (blockIdx.x * blockDim.x + threadIdx.x) >> 6;  // entry id
    const int lane = threadIdx.x & 63;
    float v = codebook[(size_t)wave * CQ + lane];
    float s = v * v;
    #pragma unroll
    for (int off = 32; off > 0; off >>= 1)
        s += __shfl_xor(s, off, 64);
    if (lane == 0) c2[wave] = s;
}

// ---------------------------------------------------------------------------
// Kernel 2: main quantizer.
// Block = 256 threads = 4 waves covering 128 rows x 256 codes:
//   wave w: rowgroup rg=w&1 (64 rows), n-half nh=w>>1 (128 codes).
// One lane per row; x[64] pinned in VGPRs via inline-asm (round-2 build
// rematerialized the invariant x loads inside the n-loop -> VGPR=40, 37%
// VALUBusy). Codebook addresses are wave-uniform -> scalar loads.
// LDS combine of the two n-halves; strict < keeps lowest n on ties.
// ---------------------------------------------------------------------------
__global__ __launch_bounds__(256, 4) void fq_main_kernel(
        const float* __restrict__ inputs,
        const float* __restrict__ codebook,
        const float* __restrict__ c2,
        float* __restrict__ out_codes,
        float* __restrict__ out_idx) {
    const int m    = blockIdx.y;
    const int w    = threadIdx.x >> 6;
    const int lane = threadIdx.x & 63;
    const int rg   = w & 1;    // row group within block
    const int nh   = w >> 1;   // n half
    const int b    = blockIdx.x * RPB + rg * 64 + lane;

    __shared__ float s_best[2][2][64];  // [rg][nh][lane]
    __shared__ int   s_bi[2][2][64];
    __shared__ int   s_win[2][64];      // final winning n per row

    // Load this row's x into registers and pin them there.
    const float* xrow = inputs + ((size_t)b * MQ + m) * CQ;
    float x[CQ];
    #pragma unroll
    for (int k = 0; k < CQ; k += 4) {
        const float4 v = *(const float4*)(xrow + k);
        x[k + 0] = v.x; x[k + 1] = v.y; x[k + 2] = v.z; x[k + 3] = v.w;
    }
    #pragma unroll
    for (int k = 0; k < CQ; ++k) asm volatile("" : "+v"(x[k]));  // no remat

    float x2 = 0.0f;
    #pragma unroll
    for (int k = 0; k < CQ; ++k) x2 = fmaf(x[k], x[k], x2);

    const float* cbm = codebook + (size_t)m * NQ * CQ;  // wave-uniform base
    const float* c2m = c2 + m * NQ;
    const int    nb  = nh * 128;

    float best = FLT_MAX;
    int   bi   = 0;
    for (int n0 = 0; n0 < 128; n0 += 4) {
        const int n = nb + n0;
        const float* cb0 = cbm + (size_t)(n + 0) * CQ;  // wave-uniform
        const float* cb1 = cbm + (size_t)(n + 1) * CQ;
        const float* cb2 = cbm + (size_t)(n + 2) * CQ;
        const float* cb3 = cbm + (size_t)(n + 3) * CQ;
        float a0 = 0.0f, a1 = 0.0f, a2 = 0.0f, a3 = 0.0f;
        #pragma unroll
        for (int k = 0; k < CQ; ++k) {
            a0 = fmaf(x[k], cb0[k], a0);
            a1 = fmaf(x[k], cb1[k], a1);
            a2 = fmaf(x[k], cb2[k], a2);
            a3 = fmaf(x[k], cb3[k], a3);
        }
        const float d0 = (x2 - 2.0f * a0) + c2m[n + 0];
        const float d1 = (x2 - 2.0f * a1) + c2m[n + 1];
        const float d2 = (x2 - 2.0f * a2) + c2m[n + 2];
        const float d3 = (x2 - 2.0f * a3) + c2m[n + 3];
        if (d0 < best) { best = d0; bi = n + 0; }
        if (d1 < best) { best = d1; bi = n + 1; }
        if (d2 < best) { best = d2; bi = n + 2; }
        if (d3 < best) { best = d3; bi = n + 3; }
    }

    s_best[rg][nh][lane] = best;
    s_bi[rg][nh][lane]   = bi;
    __syncthreads();

    if (nh == 0) {
        const float b0 = s_best[rg][0][lane];
        const float b1 = s_best[rg][1][lane];
        // strict <: half 0 (lower n) wins ties -> global argmin-first.
        const int win = (b1 < b0) ? s_bi[rg][1][lane] : s_bi[rg][0][lane];
        out_idx[(size_t)b * MQ + m] = (float)win;
        s_win[rg][lane] = win;
    }
    __syncthreads();

    // codes output: each wave writes 32 rows, lane k writes element k
    // (coalesced 256B stores; codebook row is an L1-hot broadcast load).
    const int rbase = blockIdx.x * RPB + rg * 64 + nh * 32;
    for (int j = 0; j < 32; ++j) {
        const int bn = s_win[rg][nh * 32 + j];
        out_codes[((size_t)(rbase + j) * MQ + m) * CQ + lane] =
            cbm[(size_t)bn * CQ + lane];
    }
}

extern "C" void kernel_launch(void* const* d_in, const int* in_sizes, int n_in,
                              void* d_out, int out_size, void* d_ws, size_t ws_size,
                              hipStream_t stream) {
    const float* inputs   = (const float*)d_in[0];   // [B, M, C]
    const float* codebook = (const float*)d_in[1];   // [M, N, C]
    float* out_codes = (float*)d_out;                        // [B, M, C]
    float* out_idx   = (float*)d_out + (size_t)BQ * MQ * CQ; // [B, M]
    float* c2        = (float*)d_ws;                         // [M, N] = 16 KB

    fq_c2_kernel<<<dim3((MQ * NQ) / 4), 256, 0, stream>>>(codebook, c2);

    fq_main_kernel<<<dim3(BQ / RPB, MQ), 256, 0, stream>>>(
        inputs, codebook, c2, out_codes, out_idx);
}

// Round 4
// 325.710 us; speedup vs baseline: 1.1719x; 1.1719x over previous
//
#include <hip/hip_runtime.h>
#include <float.h>

// FactoredQuantizer: B=8192, M=16, N=256, C=64
// inputs  [B, M, C] fp32
// codebook[M, N, C] fp32
// out = codes [B, M, C] fp32  ++  idx [B, M] (written as fp32 values)

#define BQ 8192
#define MQ 16
#define NQ 256
#define CQ 64
#define RPB 128   // rows per block (2 rowgroups x 64)
#define XS 66     // LDS x-row stride: 64 + 2 pad -> 2-way bank alias (free),
                  // 8B-aligned rows so float2 reads emit ds_read_b64

// ---------------------------------------------------------------------------
// Kernel 1: c2[m*N+n] = sum_k codebook[(m*N+n)*C+k]^2  (one thread per entry)
// ---------------------------------------------------------------------------
__global__ __launch_bounds__(256) void fq_c2_kernel(
        const float* __restrict__ codebook, float* __restrict__ c2) {
    const int e = blockIdx.x * 256 + threadIdx.x;  // 0..4095
    const float* row = codebook + (size_t)e * CQ;
    float s = 0.0f;
    #pragma unroll
    for (int k = 0; k < CQ; k += 4) {
        const float4 v = *(const float4*)(row + k);
        s = fmaf(v.x, v.x, fmaf(v.y, v.y, fmaf(v.z, v.z, fmaf(v.w, v.w, s))));
    }
    c2[e] = s;
}

// ---------------------------------------------------------------------------
// Kernel 2: main quantizer.
// Block = 256 threads = 4 waves: rg = w&1 (which 64 rows), nh = w>>1 (which
// 128 codes). x rows live in LDS (rounds 1-3 showed the compiler will not
// keep a 64-float per-lane array in VGPRs: remat from L1 at 37% VALUBusy, or
// scratch-spill at 20%). Codebook loads are wave-uniform -> s_load.
// ---------------------------------------------------------------------------
__global__ __launch_bounds__(256, 4) void fq_main_kernel(
        const float* __restrict__ inputs,
        const float* __restrict__ codebook,
        const float* __restrict__ c2,
        float* __restrict__ out_codes,
        float* __restrict__ out_idx) {
    const int m    = blockIdx.y;
    const int w    = threadIdx.x >> 6;
    const int lane = threadIdx.x & 63;
    const int rg   = w & 1;
    const int nh   = w >> 1;
    const int b    = blockIdx.x * RPB + rg * 64 + lane;

    __shared__ float s_x[2][64][XS];     // 33792 B
    __shared__ float s_best[2][2][64];
    __shared__ int   s_bi[2][2][64];
    __shared__ int   s_win[2][64];

    // ---- Stage 128 rows x 64 floats into LDS, coalesced float4 loads ----
    {
        const int row0 = blockIdx.x * RPB;
        #pragma unroll
        for (int i = 0; i < 8; ++i) {
            const int f = threadIdx.x + 256 * i;   // float4 id, 0..2047
            const int r = f >> 4;                  // row in block, 0..127
            const int c = (f & 15) * 4;
            const float4 v = *(const float4*)(
                inputs + ((size_t)(row0 + r) * MQ + m) * CQ + c);
            float* dst = &s_x[r >> 6][r & 63][c];
            dst[0] = v.x; dst[1] = v.y; dst[2] = v.z; dst[3] = v.w;
        }
    }
    __syncthreads();

    const float* xr  = s_x[rg][lane];                    // this lane's row
    const float* cbm = codebook + (size_t)m * NQ * CQ;   // wave-uniform base
    const float* c2m = c2 + m * NQ;

    float x2 = 0.0f;
    #pragma unroll
    for (int k = 0; k < CQ; k += 2) {
        const float2 xv = *(const float2*)(xr + k);
        x2 = fmaf(xv.x, xv.x, fmaf(xv.y, xv.y, x2));
    }

    float best = FLT_MAX;
    int   bi   = 0;
    for (int n0 = 0; n0 < 128; n0 += 4) {
        const int n = nh * 128 + n0;
        const float* cb0 = cbm + (size_t)(n + 0) * CQ;   // wave-uniform
        const float* cb1 = cbm + (size_t)(n + 1) * CQ;
        const float* cb2 = cbm + (size_t)(n + 2) * CQ;
        const float* cb3 = cbm + (size_t)(n + 3) * CQ;
        float a0 = 0.0f, a1 = 0.0f, a2 = 0.0f, a3 = 0.0f;
        #pragma unroll
        for (int k = 0; k < CQ; k += 2) {
            const float2 xv = *(const float2*)(xr + k);  // ds_read_b64
            a0 = fmaf(xv.x, cb0[k], a0); a0 = fmaf(xv.y, cb0[k + 1], a0);
            a1 = fmaf(xv.x, cb1[k], a1); a1 = fmaf(xv.y, cb1[k + 1], a1);
            a2 = fmaf(xv.x, cb2[k], a2); a2 = fmaf(xv.y, cb2[k + 1], a2);
            a3 = fmaf(xv.x, cb3[k], a3); a3 = fmaf(xv.y, cb3[k + 1], a3);
        }
        const float d0 = (x2 - 2.0f * a0) + c2m[n + 0];
        const float d1 = (x2 - 2.0f * a1) + c2m[n + 1];
        const float d2 = (x2 - 2.0f * a2) + c2m[n + 2];
        const float d3 = (x2 - 2.0f * a3) + c2m[n + 3];
        if (d0 < best) { best = d0; bi = n + 0; }  // strict <: lowest n wins
        if (d1 < best) { best = d1; bi = n + 1; }
        if (d2 < best) { best = d2; bi = n + 2; }
        if (d3 < best) { best = d3; bi = n + 3; }
    }

    s_best[rg][nh][lane] = best;
    s_bi[rg][nh][lane]   = bi;
    __syncthreads();

    if (nh == 0) {
        const float b0 = s_best[rg][0][lane];
        const float b1 = s_best[rg][1][lane];
        // strict <: half 0 (lower n) wins ties -> global argmin-first.
        const int win = (b1 < b0) ? s_bi[rg][1][lane] : s_bi[rg][0][lane];
        out_idx[(size_t)b * MQ + m] = (float)win;
        s_win[rg][lane] = win;
    }
    __syncthreads();

    // codes output: each wave writes 32 rows, lane k writes element k
    // (coalesced 256B stores; codebook row is a wave-uniform L2-hot load).
    const int rbase = blockIdx.x * RPB + rg * 64 + nh * 32;
    for (int j = 0; j < 32; ++j) {
        const int bn = s_win[rg][nh * 32 + j];
        out_codes[((size_t)(rbase + j) * MQ + m) * CQ + lane] =
            cbm[(size_t)bn * CQ + lane];
    }
}

extern "C" void kernel_launch(void* const* d_in, const int* in_sizes, int n_in,
                              void* d_out, int out_size, void* d_ws, size_t ws_size,
                              hipStream_t stream) {
    const float* inputs   = (const float*)d_in[0];   // [B, M, C]
    const float* codebook = (const float*)d_in[1];   // [M, N, C]
    float* out_codes = (float*)d_out;                        // [B, M, C]
    float* out_idx   = (float*)d_out + (size_t)BQ * MQ * CQ; // [B, M]
    float* c2        = (float*)d_ws;                         // [M, N] = 16 KB

    fq_c2_kernel<<<dim3((MQ * NQ) / 256), 256, 0, stream>>>(codebook, c2);

    fq_main_kernel<<<dim3(BQ / RPB, MQ), 256, 0, stream>>>(
        inputs, codebook, c2, out_codes, out_idx);
}

// Round 5
// 322.207 us; speedup vs baseline: 1.1847x; 1.0109x over previous
//
#include <hip/hip_runtime.h>
#include <float.h>

// FactoredQuantizer: B=8192, M=16, N=256, C=64
// inputs  [B, M, C] fp32
// codebook[M, N, C] fp32
// out = codes [B, M, C] fp32  ++  idx [B, M] (written as fp32 values)

#define BQ 8192
#define MQ 16
#define NQ 256
#define CQ 64
#define RPB 128   // rows per block (2 rowgroups x 64)
#define XS 66     // LDS x-row stride (floats): 8B-aligned rows for ds_read_b64

// ---------------------------------------------------------------------------
// Kernel 1: c2[m*N+n] = sum_k codebook[(m*N+n)*C+k]^2  (one thread per entry)
// ---------------------------------------------------------------------------
__global__ __launch_bounds__(256) void fq_c2_kernel(
        const float* __restrict__ codebook, float* __restrict__ c2) {
    const int e = blockIdx.x * 256 + threadIdx.x;  // 0..4095
    const float* row = codebook + (size_t)e * CQ;
    float s = 0.0f;
    #pragma unroll
    for (int k = 0; k < CQ; k += 4) {
        const float4 v = *(const float4*)(row + k);
        s = fmaf(v.x, v.x, fmaf(v.y, v.y, fmaf(v.z, v.z, fmaf(v.w, v.w, s))));
    }
    c2[e] = s;
}

// ---------------------------------------------------------------------------
// Kernel 2: transpose codebook[m][n][k] -> cbt[m][k][n] via LDS.
// Grid (16, 2): m, k-half. Stride-33 LDS rows -> conflict-free column reads.
// ---------------------------------------------------------------------------
__global__ __launch_bounds__(256) void fq_tr_kernel(
        const float* __restrict__ codebook, float* __restrict__ cbt) {
    const int m = blockIdx.x;
    const int h = blockIdx.y;          // k-half: k in [h*32, h*32+32)
    __shared__ float s[256][33];       // [n][k-within-half]

    // Stage: 256 rows x 32 floats = 2048 float4, 8 per thread.
    #pragma unroll
    for (int i = 0; i < 8; ++i) {
        const int f = threadIdx.x + 256 * i;   // float4 id
        const int n = f >> 3;                  // 8 float4 per row
        const int c = (f & 7) * 4;
        const float4 v = *(const float4*)(
            codebook + ((size_t)m * NQ + n) * CQ + h * 32 + c);
        s[n][c] = v.x; s[n][c + 1] = v.y; s[n][c + 2] = v.z; s[n][c + 3] = v.w;
    }
    __syncthreads();

    // Write: thread t = n; for each k, coalesced 1KB store of cbt[m][k][0:256].
    const int n = threadIdx.x;
    #pragma unroll
    for (int k = 0; k < 32; ++k)
        cbt[((size_t)m * CQ + h * 32 + k) * NQ + n] = s[n][k];
}

// ---------------------------------------------------------------------------
// Kernel 3: main quantizer, outer-product form.
// Block = 4 waves: rg = w&1 (64 rows), nh = w>>1 (128 codes).
// Per 16-code chunk: acc[16] in VGPRs; per k-pair read x once from LDS
// (ds_read_b64) and feed 32 v_fmac whose codebook operand is an SGPR
// (cbt row is wave-uniform -> s_load_dwordx16). This cuts LDS reads 8x vs
// round 4, which was LDS-pipe-bound (131k cyc LDS vs 65k VALU per CU).
// ---------------------------------------------------------------------------
__global__ __launch_bounds__(256, 4) void fq_main_kernel(
        const float* __restrict__ inputs,
        const float* __restrict__ codebook,
        const float* __restrict__ cbt,
        const float* __restrict__ c2,
        float* __restrict__ out_codes,
        float* __restrict__ out_idx) {
    const int m    = blockIdx.y;
    const int w    = threadIdx.x >> 6;
    const int lane = threadIdx.x & 63;
    const int rg   = w & 1;
    const int nh   = w >> 1;
    const int b    = blockIdx.x * RPB + rg * 64 + lane;

    __shared__ float s_x[2][64][XS];     // 33792 B
    __shared__ float s_best[2][2][64];
    __shared__ int   s_bi[2][2][64];
    __shared__ int   s_win[2][64];

    // ---- Stage 128 rows x 64 floats into LDS, coalesced float4 loads ----
    {
        const int row0 = blockIdx.x * RPB;
        #pragma unroll
        for (int i = 0; i < 8; ++i) {
            const int f = threadIdx.x + 256 * i;   // float4 id, 0..2047
            const int r = f >> 4;                  // row in block, 0..127
            const int c = (f & 15) * 4;
            const float4 v = *(const float4*)(
                inputs + ((size_t)(row0 + r) * MQ + m) * CQ + c);
            float* dst = &s_x[r >> 6][r & 63][c];
            dst[0] = v.x; dst[1] = v.y; dst[2] = v.z; dst[3] = v.w;
        }
    }
    __syncthreads();

    const float* xr    = s_x[rg][lane];                       // this lane's row
    const float* cbm   = codebook + (size_t)m * NQ * CQ;      // for gather
    const float* cbt_m = cbt + (size_t)m * CQ * NQ;           // [k][n], uniform
    const float* c2m   = c2 + m * NQ;

    float x2 = 0.0f;
    #pragma unroll
    for (int k = 0; k < CQ; k += 2) {
        const float2 xv = *(const float2*)(xr + k);
        x2 = fmaf(xv.x, xv.x, fmaf(xv.y, xv.y, x2));
    }

    float best = FLT_MAX;
    int   bi   = 0;
    for (int c0 = 0; c0 < 8; ++c0) {           // 8 chunks of 16 codes
        const int nbase = nh * 128 + c0 * 16;
        const float* cbk = cbt_m + nbase;      // wave-uniform
        float acc[16];
        #pragma unroll
        for (int j = 0; j < 16; ++j) acc[j] = 0.0f;

        #pragma unroll 4
        for (int k = 0; k < CQ; k += 2) {
            const float2 xv = *(const float2*)(xr + k);     // ds_read_b64
            const float* cb0 = cbk + (size_t)k * NQ;        // s_load_dwordx16
            const float* cb1 = cb0 + NQ;
            #pragma unroll
            for (int j = 0; j < 16; ++j) {
                acc[j] = fmaf(xv.x, cb0[j], acc[j]);
                acc[j] = fmaf(xv.y, cb1[j], acc[j]);
            }
        }
        #pragma unroll
        for (int j = 0; j < 16; ++j) {
            const float d = (x2 - 2.0f * acc[j]) + c2m[nbase + j];
            if (d < best) { best = d; bi = nbase + j; }  // strict <: lowest n
        }
    }

    s_best[rg][nh][lane] = best;
    s_bi[rg][nh][lane]   = bi;
    __syncthreads();

    if (nh == 0) {
        const float b0 = s_best[rg][0][lane];
        const float b1 = s_best[rg][1][lane];
        // strict <: half 0 (lower n) wins ties -> global argmin-first.
        const int win = (b1 < b0) ? s_bi[rg][1][lane] : s_bi[rg][0][lane];
        out_idx[(size_t)b * MQ + m] = (float)win;
        s_win[rg][lane] = win;
    }
    __syncthreads();

    // codes output: each wave writes 32 rows, lane k writes element k
    // (coalesced 256B stores; codebook row is a wave-uniform L2-hot load).
    const int rbase = blockIdx.x * RPB + rg * 64 + nh * 32;
    for (int j = 0; j < 32; ++j) {
        const int bn = s_win[rg][nh * 32 + j];
        out_codes[((size_t)(rbase + j) * MQ + m) * CQ + lane] =
            cbm[(size_t)bn * CQ + lane];
    }
}

extern "C" void kernel_launch(void* const* d_in, const int* in_sizes, int n_in,
                              void* d_out, int out_size, void* d_ws, size_t ws_size,
                              hipStream_t stream) {
    const float* inputs   = (const float*)d_in[0];   // [B, M, C]
    const float* codebook = (const float*)d_in[1];   // [M, N, C]
    float* out_codes = (float*)d_out;                        // [B, M, C]
    float* out_idx   = (float*)d_out + (size_t)BQ * MQ * CQ; // [B, M]
    float* c2        = (float*)d_ws;                         // [M, N] = 16 KB
    float* cbt       = c2 + MQ * NQ;                         // [M, C, N] = 1 MB

    fq_c2_kernel<<<dim3((MQ * NQ) / 256), 256, 0, stream>>>(codebook, c2);
    fq_tr_kernel<<<dim3(MQ, 2), 256, 0, stream>>>(codebook, cbt);

    fq_main_kernel<<<dim3(BQ / RPB, MQ), 256, 0, stream>>>(
        inputs, codebook, cbt, c2, out_codes, out_idx);
}

// Round 6
// 149.566 us; speedup vs baseline: 2.5521x; 2.1543x over previous
//
#include <hip/hip_runtime.h>
#include <float.h>

// FactoredQuantizer: B=8192, M=16, N=256, C=64
// inputs  [B, M, C] fp32;  codebook [M, N, C] fp32
// out = codes [B, M, C] fp32 ++ idx [B, M] (as fp32 values)

#define BQ 8192
#define MQ 16
#define NQ 256
#define CQ 64
#define RPB 64     // rows per block
#define XTS 68     // s_xt row stride (floats): pad for conflict-light staging

// ---------------------------------------------------------------------------
// Prep: cbt[m][k][n] = codebook[m][n][k]  AND  c2h[h][m][n] = half-sum of c^2
// Grid (16, 2). Folds c2 into the transpose pass (one read of codebook).
// ---------------------------------------------------------------------------
__global__ __launch_bounds__(256) void fq_prep_kernel(
        const float* __restrict__ codebook,
        float* __restrict__ cbt,     // [M][C][N]
        float* __restrict__ c2h) {   // [2][M][N]
    const int m = blockIdx.x;
    const int h = blockIdx.y;        // k-half
    __shared__ float s[NQ][33];

    #pragma unroll
    for (int i = 0; i < 8; ++i) {
        const int f = threadIdx.x + 256 * i;
        const int n = f >> 3;
        const int c = (f & 7) * 4;
        const float4 v = *(const float4*)(
            codebook + ((size_t)m * NQ + n) * CQ + h * 32 + c);
        s[n][c] = v.x; s[n][c + 1] = v.y; s[n][c + 2] = v.z; s[n][c + 3] = v.w;
    }
    __syncthreads();

    const int n = threadIdx.x;       // 256 threads = 256 codes
    float acc = 0.0f;
    #pragma unroll
    for (int k = 0; k < 32; ++k) {
        const float v = s[n][k];
        cbt[((size_t)m * CQ + h * 32 + k) * NQ + n] = v;
        acc = fmaf(v, v, acc);
    }
    c2h[((size_t)h * MQ + m) * NQ + n] = acc;
}

// ---------------------------------------------------------------------------
// Main: block = 4 waves, 64 rows x 256 codes. Wave w owns codes [w*64,w*64+64).
// Lane (rg=lane>>3, cg=lane&7): 8 rows (rg*8..+7) x 8 codes (cg*8..+7) = 64 acc.
// Per k: x = 2 ds_read_b128 (LDS, transposed tile), cb = 2 global dwordx4
// (L1/L2-hot cbt slab). 0.5 B/FMA on each pipe -> VALU-bound (rounds 4/5 were
// LDS-pipe-bound at 1 B/FMA; round 5's s_load path hit lgkmcnt OOO drains).
// x2 dropped: argmin(c2 - 2xc) == argmin(x2 - 2xc + c2) per row.
// ---------------------------------------------------------------------------
__global__ __launch_bounds__(256, 3) void fq_main_kernel(
        const float* __restrict__ inputs,
        const float* __restrict__ codebook,
        const float* __restrict__ cbt,
        const float* __restrict__ c2h,
        float* __restrict__ out_codes,
        float* __restrict__ out_idx) {
    const int m    = blockIdx.y;
    const int w    = threadIdx.x >> 6;
    const int lane = threadIdx.x & 63;
    const int rg   = lane >> 3;
    const int cg   = lane & 7;
    const int row0 = blockIdx.x * RPB;

    __shared__ float s_xt[CQ][XTS];   // 17408 B, [k][row]
    __shared__ float s_wb[4][RPB];    // per-wave best dist
    __shared__ int   s_wi[4][RPB];    // per-wave best idx
    __shared__ int   s_win[RPB];

    // ---- stage x transposed: [row][k] global -> s_xt[k][row] ----
    #pragma unroll
    for (int i = 0; i < 4; ++i) {
        const int f  = threadIdx.x + 256 * i;   // 0..1023 float4s
        const int r  = f >> 4;
        const int k4 = (f & 15) * 4;
        const float4 v = *(const float4*)(
            inputs + ((size_t)(row0 + r) * MQ + m) * CQ + k4);
        s_xt[k4 + 0][r] = v.x;
        s_xt[k4 + 1][r] = v.y;
        s_xt[k4 + 2][r] = v.z;
        s_xt[k4 + 3][r] = v.w;
    }
    __syncthreads();

    const int nbase = w * 64 + cg * 8;                       // first code
    const float* cbl = cbt + (size_t)m * CQ * NQ + nbase;    // + k*NQ per k

    float acc[8][8];
    #pragma unroll
    for (int i = 0; i < 8; ++i)
        #pragma unroll
        for (int j = 0; j < 8; ++j) acc[i][j] = 0.0f;

    #pragma unroll 4
    for (int k = 0; k < CQ; ++k) {
        const float4 xa = *(const float4*)&s_xt[k][rg * 8];      // ds_read_b128
        const float4 xb = *(const float4*)&s_xt[k][rg * 8 + 4];
        const float4 ca = *(const float4*)(cbl + (size_t)k * NQ);      // global
        const float4 cb = *(const float4*)(cbl + (size_t)k * NQ + 4);  // dwordx4
        const float xs[8] = {xa.x, xa.y, xa.z, xa.w, xb.x, xb.y, xb.z, xb.w};
        const float cs[8] = {ca.x, ca.y, ca.z, ca.w, cb.x, cb.y, cb.z, cb.w};
        #pragma unroll
        for (int i = 0; i < 8; ++i)
            #pragma unroll
            for (int j = 0; j < 8; ++j)
                acc[i][j] = fmaf(xs[i], cs[j], acc[i][j]);
    }

    // ---- epilogue: d = c2 - 2*acc; per-row argmin, lowest n on ties ----
    const float* c2p0 = c2h + (size_t)m * NQ + nbase;
    const float* c2p1 = c2h + (size_t)(MQ + m) * NQ + nbase;
    const float4 a0 = *(const float4*)c2p0, a1 = *(const float4*)(c2p0 + 4);
    const float4 b0 = *(const float4*)c2p1, b1 = *(const float4*)(c2p1 + 4);
    const float c2v[8] = {a0.x + b0.x, a0.y + b0.y, a0.z + b0.z, a0.w + b0.w,
                          a1.x + b1.x, a1.y + b1.y, a1.z + b1.z, a1.w + b1.w};

    float best[8]; int bib[8];
    #pragma unroll
    for (int i = 0; i < 8; ++i) {
        float bd = FLT_MAX; int bn = 0;
        #pragma unroll
        for (int j = 0; j < 8; ++j) {
            const float d = fmaf(-2.0f, acc[i][j], c2v[j]);
            if (d < bd) { bd = d; bn = nbase + j; }   // j ascending: lowest n
        }
        best[i] = bd; bib[i] = bn;
    }
    // combine across cg lanes (same rows): lane bits 0..2
    #pragma unroll
    for (int mask = 1; mask <= 4; mask <<= 1) {
        #pragma unroll
        for (int i = 0; i < 8; ++i) {
            const float od = __shfl_xor(best[i], mask, 64);
            const int   oi = __shfl_xor(bib[i],  mask, 64);
            if (od < best[i] || (od == best[i] && oi < bib[i])) {
                best[i] = od; bib[i] = oi;
            }
        }
    }
    if (cg == 0) {
        #pragma unroll
        for (int i = 0; i < 8; ++i) {
            s_wb[w][rg * 8 + i] = best[i];
            s_wi[w][rg * 8 + i] = bib[i];
        }
    }
    __syncthreads();

    // cross-wave combine: wave 0, lane = row; w ascending = n ascending
    if (w == 0) {
        const int r = lane;
        float bd = s_wb[0][r]; int bn = s_wi[0][r];
        #pragma unroll
        for (int ww = 1; ww < 4; ++ww) {
            const float od = s_wb[ww][r]; const int oi = s_wi[ww][r];
            if (od < bd || (od == bd && oi < bn)) { bd = od; bn = oi; }
        }
        s_win[r] = bn;
        out_idx[(size_t)(row0 + r) * MQ + m] = (float)bn;
    }
    __syncthreads();

    // gather codes: wave w writes rows w*16..+15, lane k = element k (256B st)
    const float* cbm = codebook + (size_t)m * NQ * CQ;
    #pragma unroll
    for (int jj = 0; jj < 16; ++jj) {
        const int r  = w * 16 + jj;
        const int bn = s_win[r];
        out_codes[((size_t)(row0 + r) * MQ + m) * CQ + lane] =
            cbm[(size_t)bn * CQ + lane];
    }
}

extern "C" void kernel_launch(void* const* d_in, const int* in_sizes, int n_in,
                              void* d_out, int out_size, void* d_ws, size_t ws_size,
                              hipStream_t stream) {
    const float* inputs   = (const float*)d_in[0];   // [B, M, C]
    const float* codebook = (const float*)d_in[1];   // [M, N, C]
    float* out_codes = (float*)d_out;                        // [B, M, C]
    float* out_idx   = (float*)d_out + (size_t)BQ * MQ * CQ; // [B, M]
    float* c2h       = (float*)d_ws;                         // [2][M][N] = 32 KB
    float* cbt       = c2h + 2 * MQ * NQ;                    // [M][C][N] = 1 MB

    fq_prep_kernel<<<dim3(MQ, 2), 256, 0, stream>>>(codebook, cbt, c2h);

    fq_main_kernel<<<dim3(BQ / RPB, MQ), 256, 0, stream>>>(
        inputs, codebook, cbt, c2h, out_codes, out_idx);
}

// Round 7
// 148.898 us; speedup vs baseline: 2.5635x; 1.0045x over previous
//
#include <hip/hip_runtime.h>
#include <float.h>

// FactoredQuantizer: B=8192, M=16, N=256, C=64
// inputs  [B, M, C] fp32;  codebook [M, N, C] fp32
// out = codes [B, M, C] fp32 ++ idx [B, M] (as fp32 values)

#define BQ 8192
#define MQ 16
#define NQ 256
#define CQ 64
#define RPB 64     // rows per block
#define XTS 68     // s_xt row stride (floats); rows use off(r) in [0,68)

// Skewed row offset: +4 floats (16B) for r>=32. The wave's 8 unique
// ds_read_b128 addresses then start at bank-quads {0,8,16,24,4,12,20,28}
// -> all 32 banks, conflict-free (round 6 had rg and rg+4 colliding: 1.8M
// conflict cycles). All offsets stay 16B-aligned for b128.
__device__ __forceinline__ int xoff(int r) { return r + ((r >> 5) << 2); }

// ---------------------------------------------------------------------------
// Prep: cbt[m][k][n] = codebook[m][n][k]  AND  c2h[h][m][n] = half-sum of c^2
// Grid (16, 2). Folds c2 into the transpose pass (one read of codebook).
// ---------------------------------------------------------------------------
__global__ __launch_bounds__(256) void fq_prep_kernel(
        const float* __restrict__ codebook,
        float* __restrict__ cbt,     // [M][C][N]
        float* __restrict__ c2h) {   // [2][M][N]
    const int m = blockIdx.x;
    const int h = blockIdx.y;        // k-half
    __shared__ float s[NQ][33];

    #pragma unroll
    for (int i = 0; i < 8; ++i) {
        const int f = threadIdx.x + 256 * i;
        const int n = f >> 3;
        const int c = (f & 7) * 4;
        const float4 v = *(const float4*)(
            codebook + ((size_t)m * NQ + n) * CQ + h * 32 + c);
        s[n][c] = v.x; s[n][c + 1] = v.y; s[n][c + 2] = v.z; s[n][c + 3] = v.w;
    }
    __syncthreads();

    const int n = threadIdx.x;       // 256 threads = 256 codes
    float acc = 0.0f;
    #pragma unroll
    for (int k = 0; k < 32; ++k) {
        const float v = s[n][k];
        cbt[((size_t)m * CQ + h * 32 + k) * NQ + n] = v;
        acc = fmaf(v, v, acc);
    }
    c2h[((size_t)h * MQ + m) * NQ + n] = acc;
}

// ---------------------------------------------------------------------------
// Main: block = 4 waves, 64 rows x 256 codes. Wave w owns codes [w*64,w*64+64).
// Lane (rg=lane>>3, cg=lane&7): 8 rows x 8 codes = 64 acc in VGPRs.
// Per k: x = 2 ds_read_b128 (skewed LDS tile, conflict-free), cb = 2 global
// dwordx4 (L1/L2-hot cbt slab) -> 0.5 B/FMA on each pipe, VALU-bound.
// x2 dropped: argmin(c2 - 2xc) == argmin(x2 - 2xc + c2) per row.
// ---------------------------------------------------------------------------
__global__ __launch_bounds__(256, 4) void fq_main_kernel(
        const float* __restrict__ inputs,
        const float* __restrict__ codebook,
        const float* __restrict__ cbt,
        const float* __restrict__ c2h,
        float* __restrict__ out_codes,
        float* __restrict__ out_idx) {
    const int m    = blockIdx.y;
    const int w    = threadIdx.x >> 6;
    const int lane = threadIdx.x & 63;
    const int rg   = lane >> 3;
    const int cg   = lane & 7;
    const int row0 = blockIdx.x * RPB;

    __shared__ float s_xt[CQ][XTS];   // 17408 B, [k][xoff(row)]
    __shared__ float s_wb[4][RPB];    // per-wave best dist
    __shared__ int   s_wi[4][RPB];    // per-wave best idx
    __shared__ int   s_win[RPB];

    // ---- stage x transposed: [row][k] global -> s_xt[k][xoff(row)] ----
    #pragma unroll
    for (int i = 0; i < 4; ++i) {
        const int f  = threadIdx.x + 256 * i;   // 0..1023 float4s
        const int r  = f >> 4;
        const int k4 = (f & 15) * 4;
        const float4 v = *(const float4*)(
            inputs + ((size_t)(row0 + r) * MQ + m) * CQ + k4);
        const int ro = xoff(r);
        s_xt[k4 + 0][ro] = v.x;
        s_xt[k4 + 1][ro] = v.y;
        s_xt[k4 + 2][ro] = v.z;
        s_xt[k4 + 3][ro] = v.w;
    }
    __syncthreads();

    const int nbase = w * 64 + cg * 8;                       // first code
    const float* cbl = cbt + (size_t)m * CQ * NQ + nbase;    // + k*NQ per k
    const int roff = xoff(rg * 8);                           // skewed row start

    float acc[8][8];
    #pragma unroll
    for (int i = 0; i < 8; ++i)
        #pragma unroll
        for (int j = 0; j < 8; ++j) acc[i][j] = 0.0f;

    #pragma unroll 4
    for (int k = 0; k < CQ; ++k) {
        const float4 xa = *(const float4*)&s_xt[k][roff];        // ds_read_b128
        const float4 xb = *(const float4*)&s_xt[k][roff + 4];
        const float4 ca = *(const float4*)(cbl + (size_t)k * NQ);      // global
        const float4 cb = *(const float4*)(cbl + (size_t)k * NQ + 4);  // dwordx4
        const float xs[8] = {xa.x, xa.y, xa.z, xa.w, xb.x, xb.y, xb.z, xb.w};
        const float cs[8] = {ca.x, ca.y, ca.z, ca.w, cb.x, cb.y, cb.z, cb.w};
        #pragma unroll
        for (int i = 0; i < 8; ++i)
            #pragma unroll
            for (int j = 0; j < 8; ++j)
                acc[i][j] = fmaf(xs[i], cs[j], acc[i][j]);
    }

    // ---- epilogue: d = c2 - 2*acc; per-row argmin, lowest n on ties ----
    const float* c2p0 = c2h + (size_t)m * NQ + nbase;
    const float* c2p1 = c2h + (size_t)(MQ + m) * NQ + nbase;
    const float4 a0 = *(const float4*)c2p0, a1 = *(const float4*)(c2p0 + 4);
    const float4 b0 = *(const float4*)c2p1, b1 = *(const float4*)(c2p1 + 4);
    const float c2v[8] = {a0.x + b0.x, a0.y + b0.y, a0.z + b0.z, a0.w + b0.w,
                          a1.x + b1.x, a1.y + b1.y, a1.z + b1.z, a1.w + b1.w};

    float best[8]; int bib[8];
    #pragma unroll
    for (int i = 0; i < 8; ++i) {
        float bd = FLT_MAX; int bn = 0;
        #pragma unroll
        for (int j = 0; j < 8; ++j) {
            const float d = fmaf(-2.0f, acc[i][j], c2v[j]);
            if (d < bd) { bd = d; bn = nbase + j; }   // j ascending: lowest n
        }
        best[i] = bd; bib[i] = bn;
    }
    // combine across cg lanes (same rows): lane bits 0..2
    #pragma unroll
    for (int mask = 1; mask <= 4; mask <<= 1) {
        #pragma unroll
        for (int i = 0; i < 8; ++i) {
            const float od = __shfl_xor(best[i], mask, 64);
            const int   oi = __shfl_xor(bib[i],  mask, 64);
            if (od < best[i] || (od == best[i] && oi < bib[i])) {
                best[i] = od; bib[i] = oi;
            }
        }
    }
    if (cg == 0) {
        #pragma unroll
        for (int i = 0; i < 8; ++i) {
            s_wb[w][rg * 8 + i] = best[i];
            s_wi[w][rg * 8 + i] = bib[i];
        }
    }
    __syncthreads();

    // cross-wave combine: wave 0, lane = row; w ascending = n ascending
    if (w == 0) {
        const int r = lane;
        float bd = s_wb[0][r]; int bn = s_wi[0][r];
        #pragma unroll
        for (int ww = 1; ww < 4; ++ww) {
            const float od = s_wb[ww][r]; const int oi = s_wi[ww][r];
            if (od < bd || (od == bd && oi < bn)) { bd = od; bn = oi; }
        }
        s_win[r] = bn;
        out_idx[(size_t)(row0 + r) * MQ + m] = (float)bn;
    }
    __syncthreads();

    // gather codes: wave w writes rows w*16..+15, lane k = element k (256B st)
    const float* cbm = codebook + (size_t)m * NQ * CQ;
    #pragma unroll
    for (int jj = 0; jj < 16; ++jj) {
        const int r  = w * 16 + jj;
        const int bn = s_win[r];
        out_codes[((size_t)(row0 + r) * MQ + m) * CQ + lane] =
            cbm[(size_t)bn * CQ + lane];
    }
}

extern "C" void kernel_launch(void* const* d_in, const int* in_sizes, int n_in,
                              void* d_out, int out_size, void* d_ws, size_t ws_size,
                              hipStream_t stream) {
    const float* inputs   = (const float*)d_in[0];   // [B, M, C]
    const float* codebook = (const float*)d_in[1];   // [M, N, C]
    float* out_codes = (float*)d_out;                        // [B, M, C]
    float* out_idx   = (float*)d_out + (size_t)BQ * MQ * CQ; // [B, M]
    float* c2h       = (float*)d_ws;                         // [2][M][N] = 32 KB
    float* cbt       = c2h + 2 * MQ * NQ;                    // [M][C][N] = 1 MB

    fq_prep_kernel<<<dim3(MQ, 2), 256, 0, stream>>>(codebook, cbt, c2h);

    fq_main_kernel<<<dim3(BQ / RPB, MQ), 256, 0, stream>>>(
        inputs, codebook, cbt, c2h, out_codes, out_idx);
}

// Round 8
// 123.231 us; speedup vs baseline: 3.0975x; 1.2083x over previous
//
#include <hip/hip_runtime.h>
#include <hip/hip_bf16.h>
#include <float.h>

// FactoredQuantizer: B=8192, M=16, N=256, C=64
// inputs  [B, M, C] fp32;  codebook [M, N, C] fp32
// out = codes [B, M, C] fp32 ++ idx [B, M] (as fp32 values)
//
// Round 8: bf16x3 split MFMA. xc computed as sum of 6 bf16 MFMA products
// (i+j<=2); error ~2^-24 relative == fp32 noise class (absmax 0 for 6 rounds).

#define BQ 8192
#define MQ 16
#define NQ 256
#define CQ 64
#define RPB 128      // rows per block
#define XP 72        // LDS row stride in bf16 elements (144 B, 16B-aligned)

typedef short  shortx8 __attribute__((ext_vector_type(8)));
typedef float  f32x4   __attribute__((ext_vector_type(4)));

__device__ __forceinline__ unsigned short f2bf(float f, float& rem) {
    __hip_bfloat16 h = __float2bfloat16(f);          // RTN
    rem = f - __bfloat162float(h);                   // exact (Sterbenz)
    return __builtin_bit_cast(unsigned short, h);
}

// ---------------------------------------------------------------------------
// Prep: for each (m,n): c2[m][n] = sum c^2 (fp32 exact), and 3-way bf16 split
// planes cb3[m][sp][n][k] (k contiguous, 64 bf16 = 128 B rows).
// ---------------------------------------------------------------------------
__global__ __launch_bounds__(256) void fq_prep_kernel(
        const float* __restrict__ codebook,
        unsigned short* __restrict__ cb3,   // [M][3][N][C] bf16
        float* __restrict__ c2) {           // [M][N]
    const int e = blockIdx.x * 256 + threadIdx.x;    // 0..4095 = m*256+n
    const int m = e >> 8, n = e & 255;
    const float* row = codebook + (size_t)e * CQ;

    float s = 0.0f;
    #pragma unroll
    for (int kc = 0; kc < CQ; kc += 8) {
        const float4 va = *(const float4*)(row + kc);
        const float4 vb = *(const float4*)(row + kc + 4);
        const float el[8] = {va.x, va.y, va.z, va.w, vb.x, vb.y, vb.z, vb.w};
        uint p0[4], p1[4], p2[4];
        #pragma unroll
        for (int u = 0; u < 4; ++u) {
            float r;
            const float a = el[2 * u], b = el[2 * u + 1];
            s = fmaf(a, a, fmaf(b, b, s));
            const unsigned short a0 = f2bf(a, r);  float ra = r;
            const unsigned short a1 = f2bf(ra, r); float ra2 = r;
            float dummy;
            const unsigned short a2 = f2bf(ra2, dummy);
            const unsigned short b0 = f2bf(b, r);  float rb = r;
            const unsigned short b1 = f2bf(rb, r); float rb2 = r;
            const unsigned short b2 = f2bf(rb2, dummy);
            p0[u] = (uint)a0 | ((uint)b0 << 16);
            p1[u] = (uint)a1 | ((uint)b1 << 16);
            p2[u] = (uint)a2 | ((uint)b2 << 16);
        }
        #pragma unroll
        for (int sp = 0; sp < 3; ++sp) {
            const uint* p = (sp == 0) ? p0 : (sp == 1) ? p1 : p2;
            uint4* dst = (uint4*)(cb3 + (((size_t)m * 3 + sp) * NQ + n) * CQ + kc);
            *dst = make_uint4(p[0], p[1], p[2], p[3]);
        }
    }
    c2[e] = s;
}

// ---------------------------------------------------------------------------
// Main: block = 4 waves; each wave: 32 rows x 256 codes via MFMA 16x16x32 bf16.
// LDS: X 3-split planes [3][128][72] + one B chunk [128][72] (split j, code
// half ch, staged 6x) -> 75 KB, 2 blocks/CU. acc[2 rowtiles][16 ntiles] f32x4.
// ---------------------------------------------------------------------------
__global__ __launch_bounds__(256, 2) void fq_main_kernel(
        const float* __restrict__ inputs,
        const float* __restrict__ codebook,
        const unsigned short* __restrict__ cb3,
        const float* __restrict__ c2,
        float* __restrict__ out_codes,
        float* __restrict__ out_idx) {
    const int m    = blockIdx.y;
    const int row0 = blockIdx.x * RPB;
    const int w    = threadIdx.x >> 6;
    const int lane = threadIdx.x & 63;
    const int quad = lane >> 4;
    const int col  = lane & 15;
    const int wrow = w * 32;          // wave's first row in block

    __shared__ unsigned short sx[3][RPB][XP];   // 55296 B
    __shared__ unsigned short sb[RPB][XP];      // 18432 B (128 codes x 64 k)
    __shared__ float s_c2[NQ];                  // 1024 B
    __shared__ int   s_bi[RPB];                 // 512 B

    // ---- stage c2 ----
    s_c2[threadIdx.x] = c2[m * NQ + threadIdx.x];

    // ---- stage X: 128 rows, fp32 -> 3 bf16 split planes ----
    {
        const int r = threadIdx.x >> 1, hh = threadIdx.x & 1;
        const float* xp = inputs + ((size_t)(row0 + r) * MQ + m) * CQ + hh * 32;
        #pragma unroll
        for (int kc = 0; kc < 32; kc += 8) {
            const float4 va = *(const float4*)(xp + kc);
            const float4 vb = *(const float4*)(xp + kc + 4);
            const float el[8] = {va.x, va.y, va.z, va.w, vb.x, vb.y, vb.z, vb.w};
            uint p0[4], p1[4], p2[4];
            #pragma unroll
            for (int u = 0; u < 4; ++u) {
                float r1, r2, dummy;
                const float a = el[2 * u], b = el[2 * u + 1];
                const unsigned short a0 = f2bf(a, r1);
                const unsigned short a1 = f2bf(r1, r2);
                const unsigned short a2 = f2bf(r2, dummy);
                const unsigned short b0 = f2bf(b, r1);
                const unsigned short b1 = f2bf(r1, r2);
                const unsigned short b2 = f2bf(r2, dummy);
                p0[u] = (uint)a0 | ((uint)b0 << 16);
                p1[u] = (uint)a1 | ((uint)b1 << 16);
                p2[u] = (uint)a2 | ((uint)b2 << 16);
            }
            uint* d0 = (uint*)&sx[0][r][hh * 32 + kc];
            uint* d1 = (uint*)&sx[1][r][hh * 32 + kc];
            uint* d2 = (uint*)&sx[2][r][hh * 32 + kc];
            #pragma unroll
            for (int u = 0; u < 4; ++u) { d0[u] = p0[u]; d1[u] = p1[u]; d2[u] = p2[u]; }
        }
    }

    f32x4 acc[2][16];
    #pragma unroll
    for (int rt = 0; rt < 2; ++rt)
        #pragma unroll
        for (int nt = 0; nt < 16; ++nt)
            acc[rt][nt] = (f32x4){0.f, 0.f, 0.f, 0.f};

    // ---- 6 sub-passes: code-half ch x codebook-split j ----
    #pragma unroll
    for (int ch = 0; ch < 2; ++ch) {
        #pragma unroll
        for (int j = 0; j < 3; ++j) {
            __syncthreads();   // prior consumption of sb done (also covers sx/c2 staging first time)
            {   // stage B: codes [ch*128, +128), split j; straight copy
                const int n = threadIdx.x >> 1, hh = threadIdx.x & 1;
                const uint4* src = (const uint4*)(
                    cb3 + (((size_t)m * 3 + j) * NQ + ch * 128 + n) * CQ + hh * 32);
                uint4* dst = (uint4*)&sb[n][hh * 32];
                #pragma unroll
                for (int q = 0; q < 4; ++q) dst[q] = src[q];
            }
            __syncthreads();

            #pragma unroll
            for (int h = 0; h < 2; ++h) {            // K halves (k = h*32..)
                shortx8 bf[8];
                #pragma unroll
                for (int ntl = 0; ntl < 8; ++ntl)
                    bf[ntl] = *(const shortx8*)&sb[ntl * 16 + col][h * 32 + quad * 8];
                #pragma unroll
                for (int i = 0; i <= 2 - j; ++i) {   // X split index
                    const shortx8 a0 = *(const shortx8*)&sx[i][wrow + col][h * 32 + quad * 8];
                    const shortx8 a1 = *(const shortx8*)&sx[i][wrow + 16 + col][h * 32 + quad * 8];
                    #pragma unroll
                    for (int ntl = 0; ntl < 8; ++ntl) {
                        acc[0][ch * 8 + ntl] = __builtin_amdgcn_mfma_f32_16x16x32_bf16(
                            a0, bf[ntl], acc[0][ch * 8 + ntl], 0, 0, 0);
                        acc[1][ch * 8 + ntl] = __builtin_amdgcn_mfma_f32_16x16x32_bf16(
                            a1, bf[ntl], acc[1][ch * 8 + ntl], 0, 0, 0);
                    }
                }
            }
        }
    }

    // ---- epilogue: d = c2 - 2*xc; per-row argmin (lowest n on ties) ----
    float c2r[16];
    #pragma unroll
    for (int nt = 0; nt < 16; ++nt) c2r[nt] = s_c2[nt * 16 + col];

    #pragma unroll
    for (int rt = 0; rt < 2; ++rt) {
        #pragma unroll
        for (int reg = 0; reg < 4; ++reg) {
            float bd = FLT_MAX; int bi = 0;
            #pragma unroll
            for (int nt = 0; nt < 16; ++nt) {        // n = nt*16+col, ascending
                const float d = fmaf(-2.0f, acc[rt][nt][reg], c2r[nt]);
                if (d < bd) { bd = d; bi = nt * 16 + col; }
            }
            // reduce across the 16 lanes of this quad-group (same rows)
            #pragma unroll
            for (int mask = 1; mask <= 8; mask <<= 1) {
                const float od = __shfl_xor(bd, mask, 64);
                const int   oi = __shfl_xor(bi, mask, 64);
                if (od < bd || (od == bd && oi < bi)) { bd = od; bi = oi; }
            }
            if (col == 0)
                s_bi[wrow + rt * 16 + quad * 4 + reg] = bi;
        }
    }
    __syncthreads();

    // ---- outputs ----
    if (threadIdx.x < RPB)
        out_idx[(size_t)(row0 + threadIdx.x) * MQ + m] = (float)s_bi[threadIdx.x];

    const float* cbm = codebook + (size_t)m * NQ * CQ;
    #pragma unroll 4
    for (int jj = 0; jj < 32; ++jj) {
        const int r  = w * 32 + jj;
        const int bn = s_bi[r];
        out_codes[((size_t)(row0 + r) * MQ + m) * CQ + lane] =
            cbm[(size_t)bn * CQ + lane];
    }
}

extern "C" void kernel_launch(void* const* d_in, const int* in_sizes, int n_in,
                              void* d_out, int out_size, void* d_ws, size_t ws_size,
                              hipStream_t stream) {
    const float* inputs   = (const float*)d_in[0];   // [B, M, C]
    const float* codebook = (const float*)d_in[1];   // [M, N, C]
    float* out_codes = (float*)d_out;                        // [B, M, C]
    float* out_idx   = (float*)d_out + (size_t)BQ * MQ * CQ; // [B, M]
    float*          c2  = (float*)d_ws;                      // 16 KB
    unsigned short* cb3 = (unsigned short*)(c2 + MQ * NQ);   // [M][3][N][C] bf16, 1.5 MB

    fq_prep_kernel<<<dim3(MQ * NQ / 256), 256, 0, stream>>>(codebook, cb3, c2);

    fq_main_kernel<<<dim3(BQ / RPB, MQ), 256, 0, stream>>>(
        inputs, codebook, cb3, c2, out_codes, out_idx);
}

// Round 9
// 120.656 us; speedup vs baseline: 3.1636x; 1.0213x over previous
//
#include <hip/hip_runtime.h>
#include <hip/hip_bf16.h>
#include <float.h>

// FactoredQuantizer: B=8192, M=16, N=256, C=64
// inputs  [B, M, C] fp32;  codebook [M, N, C] fp32
// out = codes [B, M, C] fp32 ++ idx [B, M] (as fp32 values)
//
// Round 9: bf16x3-split MFMA with B-fragments pre-laid-out in global memory
// (fragment-major), loaded as coalesced dwordx4 -> hot loop has zero LDS ops
// and zero barriers. A-fragments converted per-lane into registers.

#define BQ 8192
#define MQ 16
#define NQ 256
#define CQ 64

typedef short  shortx8 __attribute__((ext_vector_type(8)));
typedef float  f32x4   __attribute__((ext_vector_type(4)));

__device__ __forceinline__ unsigned short f2bf(float f, float& rem) {
    __hip_bfloat16 h = __float2bfloat16(f);          // RTN
    rem = f - __bfloat162float(h);                   // exact (Sterbenz)
    return __builtin_bit_cast(unsigned short, h);
}

// ---------------------------------------------------------------------------
// Prep: c2[m][n] = sum_k c^2 (fp32, wave-reduced over 8 k-chunk lanes) and
// codebook bf16x3 splits in MFMA B-fragment order:
//   cb3f[frag][lane][u], frag = ((m*3+j)*2+h)*16 + nt, lane = quad*16 + col,
//   holding codebook[m][nt*16+col][h*32+quad*8+u] split j.
// Thread t = (e, kc): e = m*256+n, kc = k-chunk (8 per row).
// ---------------------------------------------------------------------------
__global__ __launch_bounds__(256) void fq_prep_kernel(
        const float* __restrict__ codebook,
        unsigned short* __restrict__ cb3f,
        float* __restrict__ c2) {
    const int t  = blockIdx.x * 256 + threadIdx.x;   // 32768 threads
    const int kc = t & 7;
    const int e  = t >> 3;          // m*256 + n
    const int m  = e >> 8, n = e & 255;
    const int nt = n >> 4, col = n & 15;
    const int h = kc >> 2, quad = kc & 3;

    const float* src = codebook + (size_t)e * CQ + kc * 8;
    const float4 va = *(const float4*)src;
    const float4 vb = *(const float4*)(src + 4);
    const float el[8] = {va.x, va.y, va.z, va.w, vb.x, vb.y, vb.z, vb.w};

    // c2: partial sums live on 8 consecutive lanes (kc = lane&7)
    float s = 0.0f;
    #pragma unroll
    for (int u = 0; u < 8; ++u) s = fmaf(el[u], el[u], s);
    s += __shfl_xor(s, 1, 64);
    s += __shfl_xor(s, 2, 64);
    s += __shfl_xor(s, 4, 64);
    if (kc == 0) c2[e] = s;

    // 3-way bf16 split, packed 2 per dword
    uint p0[4], p1[4], p2[4];
    #pragma unroll
    for (int u = 0; u < 4; ++u) {
        float r1, r2, d;
        const float a = el[2 * u], b = el[2 * u + 1];
        const unsigned short a0 = f2bf(a, r1);
        const unsigned short a1 = f2bf(r1, r2);
        const unsigned short a2 = f2bf(r2, d);
        const unsigned short b0 = f2bf(b, r1);
        const unsigned short b1 = f2bf(r1, r2);
        const unsigned short b2 = f2bf(r2, d);
        p0[u] = (uint)a0 | ((uint)b0 << 16);
        p1[u] = (uint)a1 | ((uint)b1 << 16);
        p2[u] = (uint)a2 | ((uint)b2 << 16);
    }
    const int lane_f = quad * 16 + col;
    #pragma unroll
    for (int j = 0; j < 3; ++j) {
        const uint* p = (j == 0) ? p0 : (j == 1) ? p1 : p2;
        const int frag = ((m * 3 + j) * 2 + h) * 16 + nt;
        uint4* dst = (uint4*)(cb3f + ((size_t)frag * 64 + lane_f) * 8);
        *dst = make_uint4(p[0], p[1], p[2], p[3]);
    }
}

// ---------------------------------------------------------------------------
// Main: block = 4 waves over 64 rows x 256 codes; wave (rg=w&1, chh=w>>1)
// owns 32 rows x 128 codes: acc = 2 row-tiles x 8 n-tiles of f32x4 = 64 regs.
// X staged fp32 in LDS once; each lane converts its 12 A-fragments (i,rt,h)
// into registers. K-loop: 8 coalesced B-fragment dwordx4 loads per (h,j) then
// (3-j)*16 MFMAs. No LDS / no barriers in the hot loop.
// ---------------------------------------------------------------------------
__global__ __launch_bounds__(256, 3) void fq_main_kernel(
        const float* __restrict__ inputs,
        const float* __restrict__ codebook,
        const unsigned short* __restrict__ cb3f,
        const float* __restrict__ c2,
        float* __restrict__ out_codes,
        float* __restrict__ out_idx) {
    const int m    = blockIdx.y;
    const int row0 = blockIdx.x * 64;
    const int w    = threadIdx.x >> 6;
    const int lane = threadIdx.x & 63;
    const int quad = lane >> 4;
    const int col  = lane & 15;
    const int rg   = w & 1;    // row half
    const int chh  = w >> 1;   // code half

    __shared__ float sxf[64][68];    // 17408 B (stride 68: float4-aligned)
    __shared__ float s_c2[NQ];
    __shared__ float s_wb[2][64];
    __shared__ int   s_wi[2][64];
    __shared__ int   s_win[64];

    s_c2[threadIdx.x] = c2[m * NQ + threadIdx.x];

    // ---- stage X fp32: 64 rows x 64 floats, coalesced float4 ----
    #pragma unroll
    for (int i = 0; i < 4; ++i) {
        const int f = threadIdx.x + 256 * i;    // 0..1023 float4s
        const int r = f >> 4;
        const int c = (f & 15) * 4;
        const float4 v = *(const float4*)(
            inputs + ((size_t)(row0 + r) * MQ + m) * CQ + c);
        *(float4*)&sxf[r][c] = v;
    }
    __syncthreads();

    // ---- A-fragments: 12 (i,rt,h), converted per-lane into registers ----
    shortx8 afr[3][2][2];
    #pragma unroll
    for (int rt = 0; rt < 2; ++rt)
        #pragma unroll
        for (int h = 0; h < 2; ++h) {
            const float* xp = &sxf[rg * 32 + rt * 16 + col][h * 32 + quad * 8];
            const float4 va = *(const float4*)xp;
            const float4 vb = *(const float4*)(xp + 4);
            const float el[8] = {va.x, va.y, va.z, va.w, vb.x, vb.y, vb.z, vb.w};
            shortx8 a0, a1, a2;
            #pragma unroll
            for (int u = 0; u < 8; ++u) {
                float r1, r2, d;
                a0[u] = (short)f2bf(el[u], r1);
                a1[u] = (short)f2bf(r1, r2);
                a2[u] = (short)f2bf(r2, d);
            }
            afr[0][rt][h] = a0; afr[1][rt][h] = a1; afr[2][rt][h] = a2;
        }

    f32x4 acc[2][8];
    #pragma unroll
    for (int rt = 0; rt < 2; ++rt)
        #pragma unroll
        for (int nt = 0; nt < 8; ++nt)
            acc[rt][nt] = (f32x4){0.f, 0.f, 0.f, 0.f};

    // ---- hot loop: pure global dwordx4 + MFMA ----
    #pragma unroll
    for (int h = 0; h < 2; ++h) {
        #pragma unroll
        for (int j = 0; j < 3; ++j) {
            const int frag0 = ((m * 3 + j) * 2 + h) * 16 + chh * 8;
            const unsigned short* bp =
                cb3f + ((size_t)frag0 * 64 + lane) * 8;
            shortx8 bfr[8];
            #pragma unroll
            for (int nt = 0; nt < 8; ++nt)
                bfr[nt] = *(const shortx8*)(bp + (size_t)nt * 64 * 8);
            #pragma unroll
            for (int i = 0; i <= 2 - j; ++i) {
                #pragma unroll
                for (int nt = 0; nt < 8; ++nt) {
                    acc[0][nt] = __builtin_amdgcn_mfma_f32_16x16x32_bf16(
                        afr[i][0][h], bfr[nt], acc[0][nt], 0, 0, 0);
                    acc[1][nt] = __builtin_amdgcn_mfma_f32_16x16x32_bf16(
                        afr[i][1][h], bfr[nt], acc[1][nt], 0, 0, 0);
                }
            }
        }
    }

    // ---- epilogue: d = c2 - 2*xc; per-row argmin, lowest n on ties ----
    float c2r[8];
    #pragma unroll
    for (int nt = 0; nt < 8; ++nt)
        c2r[nt] = s_c2[chh * 128 + nt * 16 + col];

    #pragma unroll
    for (int rt = 0; rt < 2; ++rt) {
        #pragma unroll
        for (int reg = 0; reg < 4; ++reg) {
            float bd = FLT_MAX; int bi = 0;
            #pragma unroll
            for (int nt = 0; nt < 8; ++nt) {
                const float d = fmaf(-2.0f, acc[rt][nt][reg], c2r[nt]);
                if (d < bd) { bd = d; bi = chh * 128 + nt * 16 + col; }
            }
            #pragma unroll
            for (int mask = 1; mask <= 8; mask <<= 1) {   // over 16 col lanes
                const float od = __shfl_xor(bd, mask, 64);
                const int   oi = __shfl_xor(bi, mask, 64);
                if (od < bd || (od == bd && oi < bi)) { bd = od; bi = oi; }
            }
            if (col == 0) {
                const int r = rg * 32 + rt * 16 + quad * 4 + reg;
                s_wb[chh][r] = bd;
                s_wi[chh][r] = bi;
            }
        }
    }
    __syncthreads();

    // cross code-half combine (chh=0 holds lower n: ties keep it)
    if (w == 0) {
        float bd = s_wb[0][lane]; int bi = s_wi[0][lane];
        const float od = s_wb[1][lane]; const int oi = s_wi[1][lane];
        if (od < bd || (od == bd && oi < bi)) { bd = od; bi = oi; }
        s_win[lane] = bi;
        out_idx[(size_t)(row0 + lane) * MQ + m] = (float)bi;
    }
    __syncthreads();

    // gather codes: wave w writes rows w*16..+15, lane = element (256B st)
    const float* cbm = codebook + (size_t)m * NQ * CQ;
    #pragma unroll 4
    for (int jj = 0; jj < 16; ++jj) {
        const int r  = w * 16 + jj;
        const int bn = s_win[r];
        out_codes[((size_t)(row0 + r) * MQ + m) * CQ + lane] =
            cbm[(size_t)bn * CQ + lane];
    }
}

extern "C" void kernel_launch(void* const* d_in, const int* in_sizes, int n_in,
                              void* d_out, int out_size, void* d_ws, size_t ws_size,
                              hipStream_t stream) {
    const float* inputs   = (const float*)d_in[0];   // [B, M, C]
    const float* codebook = (const float*)d_in[1];   // [M, N, C]
    float* out_codes = (float*)d_out;                        // [B, M, C]
    float* out_idx   = (float*)d_out + (size_t)BQ * MQ * CQ; // [B, M]
    float*          c2   = (float*)d_ws;                     // 16 KB
    unsigned short* cb3f = (unsigned short*)(c2 + MQ * NQ);  // 1.5 MB

    fq_prep_kernel<<<dim3(128), 256, 0, stream>>>(codebook, cb3f, c2);

    fq_main_kernel<<<dim3(BQ / 64, MQ), 256, 0, stream>>>(
        inputs, codebook, cb3f, c2, out_codes, out_idx);
}